// Round 7
// baseline (98.899 us; speedup 1.0000x reference)
//
#include <hip/hip_runtime.h>
#include <hip/hip_bf16.h>
#include <stdint.h>

#define Bn 8192
#define Dk 512

typedef __attribute__((ext_vector_type(8))) short short8;
typedef __attribute__((ext_vector_type(4))) float f32x4;

// fp32 -> bf16 bits, round-to-nearest-even
__device__ __forceinline__ unsigned short f2bf(float f) {
  unsigned int u = __float_as_uint(f);
  u += 0x7FFFu + ((u >> 16) & 1u);
  return (unsigned short)(u >> 16);
}

// async global -> LDS, 16 bytes per lane (dest = wave-uniform base + lane*16)
__device__ __forceinline__ void gload_lds16(const unsigned short* g, const short* l) {
  __builtin_amdgcn_global_load_lds(
      (const __attribute__((address_space(1))) void*)g,
      (__attribute__((address_space(3))) void*)l,
      16, 0, 0);
}

// ---------------------------------------------------------------------------
// Kernel 1: cast fp32 embeddings to bf16 (for MFMA) + exact fp32 row norms.
// ---------------------------------------------------------------------------
__global__ __launch_bounds__(256) void prep_kernel(
    const float* __restrict__ T, const float* __restrict__ M,
    unsigned short* __restrict__ Tb, unsigned short* __restrict__ Mb,
    float* __restrict__ tn, float* __restrict__ mn)
{
  const int bid = blockIdx.x;
  const int row = bid & (Bn - 1);
  const bool isM = bid >= Bn;
  const float* __restrict__ src = isM ? M : T;
  unsigned short* __restrict__ dst = isM ? Mb : Tb;
  const int tid = threadIdx.x;

  float2 v = reinterpret_cast<const float2*>(src + (size_t)row * Dk)[tid];
  float s = v.x * v.x + v.y * v.y;
  unsigned int packed = (unsigned int)f2bf(v.x) | ((unsigned int)f2bf(v.y) << 16);
  reinterpret_cast<unsigned int*>(dst + (size_t)row * Dk)[tid] = packed;

  #pragma unroll
  for (int off = 32; off >= 1; off >>= 1) s += __shfl_xor(s, off, 64);
  __shared__ float ws4[4];
  const int wave = tid >> 6, lane = tid & 63;
  if (lane == 0) ws4[wave] = s;
  __syncthreads();
  if (tid == 0) {
    float* nrm = isM ? mn : tn;
    nrm[row] = ws4[0] + ws4[1] + ws4[2] + ws4[3];
  }
}

// ---------------------------------------------------------------------------
// Kernel 2: 256x256-tile bf16 MFMA GEMM, BK=32, 4-deep LDS ring, 8-phase
// schedule (m201 template): per K-step two phases of 16 MFMA, each phase =
// { ds_read subtile (8 or 4 x b128) ; 2 x global_load_lds ; [vmcnt(4) in P1]
//   ; BAR ; lgkmcnt(0)+sched_barrier ; setprio(1) 16 MFMA setprio(0) ; BAR }.
// vmcnt(4) once per K-step: only tile kt+2's 4 loads remain in flight =>
// tile kt+1 is resident before its P0 reads (in-order retirement, m135).
// Phase accumulators are disjoint (image rows 0-3 vs 4-7) so phases never
// serialize on acc. Ring safety: buf kt-2 is overwritten at P(kt,*); its
// last reads were >=3 collective barriers earlier.
// ---------------------------------------------------------------------------
__global__ __launch_bounds__(512, 2) void gemm_epi_kernel(
    const unsigned short* __restrict__ Tb, const unsigned short* __restrict__ Mb,
    const float* __restrict__ tn, const float* __restrict__ mn,
    const int* __restrict__ groups,
    float2* __restrict__ part)
{
  extern __shared__ char smem[];
  short* As = (short*)smem;                    // text tiles: 4 bufs x 256x32 bf16
  short* Bs = As + 4 * 8192;                   // image tiles: 4 bufs
  float2* tg_s = (float2*)(Bs + 4 * 8192);     // 256 (text norm, group bits)
  float2* mg_s = tg_s + 256;                   // 256 (image norm, group bits)

  const int tid = threadIdx.x;
  const int wave = tid >> 6;
  const int lane = tid & 63;
  const int llo = lane & 15, lhi = lane >> 4;

  // XCD-compact swizzle: 1024 blocks = 8 XCDs x (4 by x 32 bx), B-panel-major
  const int bid = blockIdx.x;
  const int xcd = bid & 7, lidx = bid >> 3;
  const int by = xcd * 4 + (lidx & 3);
  const int bx = lidx >> 2;
  const int brow = by * 256;   // text rows
  const int bcol = bx * 256;   // image rows

  const int ir = wave >> 2;    // image half: rows ir*128 .. +128
  const int tc = wave & 3;     // text quarter: cols tc*64 .. +64

  if (tid < 256) {
    tg_s[tid] = make_float2(tn[brow + tid], __uint_as_float((unsigned)groups[brow + tid]));
  } else {
    const int t = tid - 256;
    mg_s[t] = make_float2(mn[bcol + t], __uint_as_float((unsigned)groups[bcol + t]));
  }

  // staging geometry: K-tile = 256 rows x 32 bf16 = 1024 chunks of 16B;
  // 512 threads -> 2 issues per operand. Pre-swizzled global source (rule #21).
  int ldsoff[2];
  unsigned goffT[2], goffM[2];
  #pragma unroll
  for (int i = 0; i < 2; ++i) {
    const int c = i * 512 + tid;
    const int row = c >> 2;
    const int sc = (c & 3) ^ ((row >> 1) & 3);
    goffT[i] = (unsigned)(brow + row) * Dk + sc * 8;
    goffM[i] = (unsigned)(bcol + row) * Dk + sc * 8;
    ldsoff[i] = (i * 512 + wave * 64) * 8;     // wave-uniform chunk base (shorts)
  }

  auto stageT = [&](int kt, int buf) {     // text half-stage: 2 gloads
    const int k0 = kt * 32;
    gload_lds16(Tb + goffT[0] + k0, As + buf * 8192 + ldsoff[0]);
    gload_lds16(Tb + goffT[1] + k0, As + buf * 8192 + ldsoff[1]);
  };
  auto stageI = [&](int kt, int buf) {     // image half-stage: 2 gloads
    const int k0 = kt * 32;
    gload_lds16(Mb + goffM[0] + k0, Bs + buf * 8192 + ldsoff[0]);
    gload_lds16(Mb + goffM[1] + k0, Bs + buf * 8192 + ldsoff[1]);
  };

  // fragment read offsets (XOR-swizzled, kt-independent; row stride 32 shorts)
  int toff[4], moff[8];
  #pragma unroll
  for (int jt = 0; jt < 4; ++jt) {
    const int r = tc * 64 + jt * 16 + llo;
    toff[jt] = r * 32 + (lhi ^ ((r >> 1) & 3)) * 8;
  }
  #pragma unroll
  for (int it = 0; it < 8; ++it) {
    const int r = ir * 128 + it * 16 + llo;
    moff[it] = r * 32 + (lhi ^ ((r >> 1) & 3)) * 8;
  }

  f32x4 acc[8][4];
  #pragma unroll
  for (int it = 0; it < 8; ++it)
    #pragma unroll
    for (int jt = 0; jt < 4; ++jt)
      acc[it][jt] = f32x4{0.f, 0.f, 0.f, 0.f};

  // prologue: tiles 0,1 staged; tile 0 resident before first reads
  stageT(0, 0); stageI(0, 0); stageT(1, 1); stageI(1, 1);
  asm volatile("s_waitcnt vmcnt(4)" ::: "memory");
  __builtin_amdgcn_s_barrier();
  int kt = 0;

#define STEP(BUF, DO_STAGE, VMC)                                               \
  do {                                                                         \
    /* ---------- phase 0: image rows 0..3 ---------- */                       \
    short8 tf[4], mf0[4];                                                      \
    _Pragma("unroll")                                                          \
    for (int jt = 0; jt < 4; ++jt)                                             \
      tf[jt] = *reinterpret_cast<const short8*>(&As[(BUF) * 8192 + toff[jt]]); \
    _Pragma("unroll")                                                          \
    for (int it = 0; it < 4; ++it)                                             \
      mf0[it] = *reinterpret_cast<const short8*>(&Bs[(BUF) * 8192 + moff[it]]);\
    if (DO_STAGE) stageT(kt + 2, ((BUF) + 2) & 3);                             \
    __builtin_amdgcn_s_barrier();                                              \
    asm volatile("s_waitcnt lgkmcnt(0)" ::: "memory");                         \
    __builtin_amdgcn_sched_barrier(0);                                         \
    __builtin_amdgcn_s_setprio(1);                                             \
    _Pragma("unroll")                                                          \
    for (int it = 0; it < 4; ++it)                                             \
      _Pragma("unroll")                                                        \
      for (int jt = 0; jt < 4; ++jt)                                           \
        acc[it][jt] = __builtin_amdgcn_mfma_f32_16x16x32_bf16(                 \
            mf0[it], tf[jt], acc[it][jt], 0, 0, 0);                            \
    __builtin_amdgcn_s_setprio(0);                                             \
    __builtin_amdgcn_s_barrier();                                              \
    /* ---------- phase 1: image rows 4..7 ---------- */                       \
    short8 mf1[4];                                                             \
    _Pragma("unroll")                                                          \
    for (int it = 0; it < 4; ++it)                                             \
      mf1[it] = *reinterpret_cast<const short8*>(                              \
          &Bs[(BUF) * 8192 + moff[4 + it]]);                                   \
    if (DO_STAGE) stageI(kt + 2, ((BUF) + 2) & 3);                             \
    asm volatile("s_waitcnt vmcnt(" #VMC ")" ::: "memory");                    \
    __builtin_amdgcn_s_barrier();                                              \
    asm volatile("s_waitcnt lgkmcnt(0)" ::: "memory");                         \
    __builtin_amdgcn_sched_barrier(0);                                         \
    __builtin_amdgcn_s_setprio(1);                                             \
    _Pragma("unroll")                                                          \
    for (int it = 0; it < 4; ++it)                                             \
      _Pragma("unroll")                                                        \
      for (int jt = 0; jt < 4; ++jt)                                           \
        acc[4 + it][jt] = __builtin_amdgcn_mfma_f32_16x16x32_bf16(             \
            mf1[it], tf[jt], acc[4 + it][jt], 0, 0, 0);                        \
    __builtin_amdgcn_s_setprio(0);                                             \
    __builtin_amdgcn_s_barrier();                                              \
    ++kt;                                                                      \
  } while (0)

  #pragma unroll 1
  for (int ko = 0; ko < 3; ++ko) {
    STEP(0, true, 4); STEP(1, true, 4); STEP(2, true, 4); STEP(3, true, 4);
  }
  STEP(0, true,  4);   // kt=12: stages tile 14
  STEP(1, true,  4);   // kt=13: stages tile 15; vmcnt(4) -> tile 14 resident
  STEP(2, false, 0);   // kt=14: vmcnt(0) -> tile 15 resident
  STEP(3, false, 0);   // kt=15: drain (no-op wait)
#undef STEP

  // ---- fused epilogue (no atomics) ----
  // acc[it][jt][r] on lane (llo,lhi) = dot(image[bcol+ir*128+it*16+lhi*4+r],
  //                                        text [brow+tc*64+jt*16+llo])
  float2* red = reinterpret_cast<float2*>(As);   // 16 KB alias on buf0 (dead)

  #pragma unroll
  for (int jt = 0; jt < 4; ++jt) {
    const int tl = tc * 64 + jt * 16 + llo;
    const float2 tg = tg_s[tl];
    const unsigned gt = __float_as_uint(tg.y);
    float nv = 0.f, dv = 0.f;
    #pragma unroll
    for (int it = 0; it < 8; ++it) {
      #pragma unroll
      for (int r = 0; r < 4; ++r) {
        const float2 mg = mg_s[ir * 128 + it * 16 + lhi * 4 + r];
        const float sq = fmaxf(tg.x + mg.x - 2.0f * acc[it][jt][r], 0.f);
        const float sim = __builtin_amdgcn_exp2f(-1.4426950408889634f *
                                                 __builtin_amdgcn_sqrtf(sq));
        if (gt == __float_as_uint(mg.y)) nv += sim; else dv += sim;
      }
    }
    red[(ir * 4 + lhi) * 256 + tl] = make_float2(nv, dv);
  }
  __syncthreads();
  if (tid < 256) {
    float nv = 0.f, dv = 0.f;
    #pragma unroll
    for (int s = 0; s < 8; ++s) {
      const float2 v = red[s * 256 + tid];
      nv += v.x; dv += v.y;
    }
    part[(size_t)bx * Bn + brow + tid] = make_float2(nv, dv);
  }
}

// ---------------------------------------------------------------------------
// Kernel 3a: per-row sum over 32 image-panel partials + loss term -> block sums.
// Kernel 3b: final reduce of 32 block sums.
// ---------------------------------------------------------------------------
__global__ __launch_bounds__(256) void finalize1_kernel(
    const float2* __restrict__ part, float* __restrict__ bsum)
{
  const int i = blockIdx.x * 256 + threadIdx.x;
  float nv = 0.f, dv = 0.f;
  #pragma unroll 8
  for (int p = 0; p < 32; ++p) {
    const float2 v = part[(size_t)p * Bn + i];
    nv += v.x; dv += v.y;
  }
  float li = (nv > 0.f && dv > 0.f)
      ? (__builtin_amdgcn_logf(dv) - __builtin_amdgcn_logf(nv)) * 0.69314718055994531f
      : 0.f;
  #pragma unroll
  for (int off = 32; off >= 1; off >>= 1) li += __shfl_xor(li, off, 64);
  __shared__ float ws4[4];
  if ((threadIdx.x & 63) == 0) ws4[threadIdx.x >> 6] = li;
  __syncthreads();
  if (threadIdx.x == 0) bsum[blockIdx.x] = ws4[0] + ws4[1] + ws4[2] + ws4[3];
}

__global__ void finalize2_kernel(const float* __restrict__ bsum, float* __restrict__ out)
{
  float s = (threadIdx.x < 32) ? bsum[threadIdx.x] : 0.f;
  #pragma unroll
  for (int off = 32; off >= 1; off >>= 1) s += __shfl_xor(s, off, 64);
  if (threadIdx.x == 0) out[0] = s / (float)Bn;
}

// ---------------------------------------------------------------------------
extern "C" void kernel_launch(void* const* d_in, const int* in_sizes, int n_in,
                              void* d_out, int out_size, void* d_ws, size_t ws_size,
                              hipStream_t stream) {
  const float* T = (const float*)d_in[0];
  const float* M = (const float*)d_in[1];
  const int* groups = (const int*)d_in[2];

  char* ws = (char*)d_ws;
  unsigned short* Tb = (unsigned short*)ws;                          // 8 MB
  unsigned short* Mb = (unsigned short*)(ws + (size_t)Bn * Dk * 2);  // 8 MB
  float* tn  = (float*)(ws + (size_t)Bn * Dk * 4);                   // 32 KB
  float* mn  = tn + Bn;                                              // 32 KB
  float2* part = (float2*)(mn + Bn);                                 // 2 MB (32 x 8192)
  float* bsum = (float*)(part + (size_t)32 * Bn);                    // 128 B

  const int smem_bytes = 4 * 8192 * 2 * 2 + 512 * 8;   // 128 KB tiles + 4 KB norms
  hipFuncSetAttribute((const void*)gemm_epi_kernel,
                      hipFuncAttributeMaxDynamicSharedMemorySize, smem_bytes);

  prep_kernel<<<2 * Bn, 256, 0, stream>>>(T, M, Tb, Mb, tn, mn);
  gemm_epi_kernel<<<1024, 512, smem_bytes, stream>>>(Tb, Mb, tn, mn, groups, part);
  finalize1_kernel<<<Bn / 256, 256, 0, stream>>>(part, bsum);
  finalize2_kernel<<<1, 64, 0, stream>>>(bsum, (float*)d_out);
}

// Round 8
// 68.102 us; speedup vs baseline: 1.4522x; 1.4522x over previous
//
#include <hip/hip_runtime.h>
#include <hip/hip_bf16.h>
#include <stdint.h>

#define Bn 8192
#define Dk 512
#define SCALE1 0x7F7F7F7F   // e8m0 127 (=1.0) in every byte: opsel-proof

typedef __attribute__((ext_vector_type(8))) int   int8v;
typedef __attribute__((ext_vector_type(4))) int   int4v;
typedef __attribute__((ext_vector_type(16))) float f32x16;

// async global -> LDS, 16 bytes per lane (dest = wave-uniform base + lane*16)
__device__ __forceinline__ void gload_lds16(const uint8_t* g, const uint8_t* l) {
  __builtin_amdgcn_global_load_lds(
      (const __attribute__((address_space(1))) void*)g,
      (__attribute__((address_space(3))) void*)l,
      16, 0, 0);
}

// ---------------------------------------------------------------------------
// Kernel 1: cast fp32 embeddings to fp8 e4m3 (for MX MFMA) + exact fp32 norms.
// 128 threads = 1 row (4 floats/thread -> packed 4 fp8 bytes).
// ---------------------------------------------------------------------------
__global__ __launch_bounds__(128) void prep_kernel(
    const float* __restrict__ T, const float* __restrict__ M,
    uint8_t* __restrict__ Tq, uint8_t* __restrict__ Mq,
    float* __restrict__ tn, float* __restrict__ mn)
{
  const int bid = blockIdx.x;
  const int row = bid & (Bn - 1);
  const bool isM = bid >= Bn;
  const float* __restrict__ src = isM ? M : T;
  unsigned* __restrict__ dst = (unsigned*)(isM ? Mq : Tq);
  const int tid = threadIdx.x;

  float4 v = reinterpret_cast<const float4*>(src + (size_t)row * Dk)[tid];
  float s = v.x * v.x + v.y * v.y + v.z * v.z + v.w * v.w;
  int p = __builtin_amdgcn_cvt_pk_fp8_f32(v.x, v.y, 0, false);
  p = __builtin_amdgcn_cvt_pk_fp8_f32(v.z, v.w, p, true);
  dst[(size_t)row * 128 + tid] = (unsigned)p;

  #pragma unroll
  for (int off = 32; off >= 1; off >>= 1) s += __shfl_xor(s, off, 64);
  __shared__ float ws2[2];
  if ((tid & 63) == 0) ws2[tid >> 6] = s;
  __syncthreads();
  if (tid == 0) (isM ? mn : tn)[row] = ws2[0] + ws2[1];
}

// ---------------------------------------------------------------------------
// Kernel 2: 256x256-tile MX-fp8 GEMM (scale=1.0), BK=64, 4-deep LDS ring,
// prefetch depth 2, R6-verified barrier cadence (bar every 2 steps, counted
// vmcnt(8), never 0 until tail). 8 waves (2 image x 4 text); per wave per
// K-step: 8x mfma_scale_f32_32x32x64_f8f6f4 (image frag = A, text = B so
// D col = text index), 12x ds_read_b128. Fused atomic-free epilogue.
// Fragment layout: row = lane&31, k = (lane>>5)*32 + byte;
// C/D: col = lane&31, row = (reg&3)+8*(reg>>2)+4*(lane>>5)  [m101/m127].
// ---------------------------------------------------------------------------
__global__ __launch_bounds__(512, 2) void gemm_epi_kernel(
    const uint8_t* __restrict__ Tq, const uint8_t* __restrict__ Mq,
    const float* __restrict__ tn, const float* __restrict__ mn,
    const int* __restrict__ groups,
    float2* __restrict__ part)
{
  extern __shared__ char smem[];
  uint8_t* As8 = (uint8_t*)smem;           // text tiles: 4 bufs x 256x64 fp8
  uint8_t* Bs8 = As8 + 4 * 16384;          // image tiles: 4 bufs
  float2* tg_s = (float2*)(Bs8 + 4 * 16384);  // 256 (text norm, group bits)
  float2* mg_s = tg_s + 256;                  // 256 (image norm, group bits)

  const int tid = threadIdx.x;
  const int wave = tid >> 6;
  const int lane = tid & 63;
  const int l31 = lane & 31, h = lane >> 5;

  // XCD-compact swizzle: 1024 blocks = 8 XCDs x (4 by x 32 bx), B-panel-major
  const int bid = blockIdx.x;
  const int xcd = bid & 7, lidx = bid >> 3;
  const int by = xcd * 4 + (lidx & 3);
  const int bx = lidx >> 2;
  const int brow = by * 256;   // text rows
  const int bcol = bx * 256;   // image rows

  const int ir = wave >> 2;    // image half: rows ir*128 .. +128
  const int tc = wave & 3;     // text quarter: cols tc*64 .. +64

  if (tid < 256) {
    tg_s[tid] = make_float2(tn[brow + tid], __uint_as_float((unsigned)groups[brow + tid]));
  } else {
    const int t = tid - 256;
    mg_s[t] = make_float2(mn[bcol + t], __uint_as_float((unsigned)groups[bcol + t]));
  }

  // staging: K-tile = 256 rows x 64 B = 1024 chunks of 16 B per operand;
  // 512 threads -> 2 chunks per thread per operand. XOR-swizzled source
  // (rule #21): LDS slot s of row r holds k-chunk s ^ ((r>>1)&3).
  int ldsoff[2];
  unsigned goffT[2], goffM[2];   // byte offsets
  #pragma unroll
  for (int i = 0; i < 2; ++i) {
    const int c = i * 512 + tid;
    const int row = c >> 2;
    const int sc = (c & 3) ^ ((row >> 1) & 3);
    goffT[i] = (unsigned)(brow + row) * Dk + sc * 16;
    goffM[i] = (unsigned)(bcol + row) * Dk + sc * 16;
    ldsoff[i] = (i * 512 + wave * 64) * 16;   // wave-uniform byte base
  }

  auto stage = [&](int t, int buf) {
    const int k0 = t * 64;   // byte offset along the row
    #pragma unroll
    for (int i = 0; i < 2; ++i) {
      gload_lds16(Tq + goffT[i] + k0, As8 + buf * 16384 + ldsoff[i]);
      gload_lds16(Mq + goffM[i] + k0, Bs8 + buf * 16384 + ldsoff[i]);
    }
  };

  // fragment read offsets (kt-independent). Lane needs row r, k-chunks
  // {2h, 2h+1} (16 fp8 each); swizzled slot = chunk ^ ((r>>1)&3); the pair
  // stays XOR-16-adjacent: second read at offset^16.
  int toffB[2], moffB[4];
  #pragma unroll
  for (int jt = 0; jt < 2; ++jt) {
    const int r = tc * 64 + jt * 32 + l31;
    toffB[jt] = r * 64 + (((h << 1) ^ ((r >> 1) & 3)) << 4);
  }
  #pragma unroll
  for (int it = 0; it < 4; ++it) {
    const int r = ir * 128 + it * 32 + l31;
    moffB[it] = r * 64 + (((h << 1) ^ ((r >> 1) & 3)) << 4);
  }

  f32x16 acc[4][2];
  #pragma unroll
  for (int it = 0; it < 4; ++it)
    #pragma unroll
    for (int jt = 0; jt < 2; ++jt)
      #pragma unroll
      for (int e = 0; e < 16; ++e)
        acc[it][jt][e] = 0.f;

  // prologue: tiles 0,1 staged; tile 0 resident before first reads
  stage(0, 0); stage(1, 1);
  asm volatile("s_waitcnt vmcnt(4)" ::: "memory");
  __builtin_amdgcn_s_barrier();
  int kt = 0;

#define STEP(BUF, DO_STAGE, DO_BAR, VMC)                                       \
  do {                                                                         \
    if (DO_BAR) __builtin_amdgcn_s_barrier();                                  \
    if (DO_STAGE) stage(kt + 2, ((BUF) + 2) & 3);                              \
    asm volatile("s_waitcnt vmcnt(" #VMC ")" ::: "memory");                    \
    int8v tf[2], mf[4];                                                        \
    _Pragma("unroll")                                                          \
    for (int jt = 0; jt < 2; ++jt) {                                           \
      int4v lo = *(const int4v*)(As8 + (BUF) * 16384 + toffB[jt]);             \
      int4v hi = *(const int4v*)(As8 + (BUF) * 16384 + (toffB[jt] ^ 16));      \
      tf[jt] = __builtin_shufflevector(lo, hi, 0, 1, 2, 3, 4, 5, 6, 7);        \
    }                                                                          \
    _Pragma("unroll")                                                          \
    for (int it = 0; it < 4; ++it) {                                           \
      int4v lo = *(const int4v*)(Bs8 + (BUF) * 16384 + moffB[it]);             \
      int4v hi = *(const int4v*)(Bs8 + (BUF) * 16384 + (moffB[it] ^ 16));      \
      mf[it] = __builtin_shufflevector(lo, hi, 0, 1, 2, 3, 4, 5, 6, 7);        \
    }                                                                          \
    __builtin_amdgcn_s_setprio(1);                                             \
    _Pragma("unroll")                                                          \
    for (int it = 0; it < 4; ++it)                                             \
      _Pragma("unroll")                                                        \
      for (int jt = 0; jt < 2; ++jt)                                           \
        acc[it][jt] = __builtin_amdgcn_mfma_scale_f32_32x32x64_f8f6f4(         \
            mf[it], tf[jt], acc[it][jt], 0, 0, 0, SCALE1, 0, SCALE1);          \
    __builtin_amdgcn_s_setprio(0);                                             \
    ++kt;                                                                      \
  } while (0)

  STEP(0, true,  true,  8);   // kt=0: stages tile 2
  STEP(1, true,  false, 8);   // kt=1: tile 3
  STEP(2, true,  true,  8);   // kt=2: tile 4
  STEP(3, true,  false, 8);   // kt=3: tile 5
  STEP(0, true,  true,  8);   // kt=4: tile 6
  STEP(1, true,  false, 8);   // kt=5: tile 7 (last)
  STEP(2, false, true,  4);   // kt=6: tiles 6,7 outstanding -> wait to 4
  STEP(3, false, false, 0);   // kt=7: drain
#undef STEP

  // ---- fused epilogue (no atomics) ----
  // acc[it][jt][reg] on lane (l31,h) = dot(image[bcol+ir*128+it*32+crow],
  //                                        text [brow+tc*64+jt*32+l31])
  // with crow = (reg&3) + 8*(reg>>2) + 4*h.
  float2* red = reinterpret_cast<float2*>(As8);   // 8 KB alias on buf0 (dead)

  float nv[2] = {0.f, 0.f}, dv[2] = {0.f, 0.f};
  const int tl0 = tc * 64 + l31;
  const float2 tgA = tg_s[tl0];
  const float2 tgB = tg_s[tl0 + 32];
  #pragma unroll
  for (int it = 0; it < 4; ++it) {
    #pragma unroll
    for (int reg = 0; reg < 16; ++reg) {
      const int crow = (reg & 3) + 8 * (reg >> 2) + 4 * h;
      const float2 mg = mg_s[ir * 128 + it * 32 + crow];
      const unsigned gm = __float_as_uint(mg.y);
      {
        const float sq = fmaxf(tgA.x + mg.x - 2.0f * acc[it][0][reg], 0.f);
        const float sim = __builtin_amdgcn_exp2f(-1.4426950408889634f *
                                                 __builtin_amdgcn_sqrtf(sq));
        if (__float_as_uint(tgA.y) == gm) nv[0] += sim; else dv[0] += sim;
      }
      {
        const float sq = fmaxf(tgB.x + mg.x - 2.0f * acc[it][1][reg], 0.f);
        const float sim = __builtin_amdgcn_exp2f(-1.4426950408889634f *
                                                 __builtin_amdgcn_sqrtf(sq));
        if (__float_as_uint(tgB.y) == gm) nv[1] += sim; else dv[1] += sim;
      }
    }
  }
  __syncthreads();   // all waves done with LDS tile bufs before red alias
  const int slot = ir * 2 + h;
  red[slot * 256 + tl0]      = make_float2(nv[0], dv[0]);
  red[slot * 256 + tl0 + 32] = make_float2(nv[1], dv[1]);
  __syncthreads();
  if (tid < 256) {
    float n = 0.f, d = 0.f;
    #pragma unroll
    for (int s = 0; s < 4; ++s) {
      const float2 v = red[s * 256 + tid];
      n += v.x; d += v.y;
    }
    part[(size_t)bx * Bn + brow + tid] = make_float2(n, d);
  }
}

// ---------------------------------------------------------------------------
// Kernel 3a: per-row sum over 32 image-panel partials + loss term -> block sums.
// Kernel 3b: final reduce of 32 block sums.
// ---------------------------------------------------------------------------
__global__ __launch_bounds__(256) void finalize1_kernel(
    const float2* __restrict__ part, float* __restrict__ bsum)
{
  const int i = blockIdx.x * 256 + threadIdx.x;
  float nv = 0.f, dv = 0.f;
  #pragma unroll 8
  for (int p = 0; p < 32; ++p) {
    const float2 v = part[(size_t)p * Bn + i];
    nv += v.x; dv += v.y;
  }
  float li = (nv > 0.f && dv > 0.f)
      ? (__builtin_amdgcn_logf(dv) - __builtin_amdgcn_logf(nv)) * 0.69314718055994531f
      : 0.f;
  #pragma unroll
  for (int off = 32; off >= 1; off >>= 1) li += __shfl_xor(li, off, 64);
  __shared__ float ws4[4];
  if ((threadIdx.x & 63) == 0) ws4[threadIdx.x >> 6] = li;
  __syncthreads();
  if (threadIdx.x == 0) bsum[blockIdx.x] = ws4[0] + ws4[1] + ws4[2] + ws4[3];
}

__global__ void finalize2_kernel(const float* __restrict__ bsum, float* __restrict__ out)
{
  float s = (threadIdx.x < 32) ? bsum[threadIdx.x] : 0.f;
  #pragma unroll
  for (int off = 32; off >= 1; off >>= 1) s += __shfl_xor(s, off, 64);
  if (threadIdx.x == 0) out[0] = s / (float)Bn;
}

// ---------------------------------------------------------------------------
extern "C" void kernel_launch(void* const* d_in, const int* in_sizes, int n_in,
                              void* d_out, int out_size, void* d_ws, size_t ws_size,
                              hipStream_t stream) {
  const float* T = (const float*)d_in[0];
  const float* M = (const float*)d_in[1];
  const int* groups = (const int*)d_in[2];

  char* ws = (char*)d_ws;
  uint8_t* Tq = (uint8_t*)ws;                                   // 4 MB fp8 text
  uint8_t* Mq = (uint8_t*)(ws + (size_t)Bn * Dk);               // 4 MB fp8 image
  float* tn  = (float*)(ws + (size_t)Bn * Dk * 2);              // 32 KB
  float* mn  = tn + Bn;                                         // 32 KB
  float2* part = (float2*)(mn + Bn);                            // 2 MB (32 x 8192)
  float* bsum = (float*)(part + (size_t)32 * Bn);               // 128 B

  const int smem_bytes = 8 * 16384 + 512 * 8;   // 128 KB tiles + 4 KB norms
  hipFuncSetAttribute((const void*)gemm_epi_kernel,
                      hipFuncAttributeMaxDynamicSharedMemorySize, smem_bytes);

  prep_kernel<<<2 * Bn, 128, 0, stream>>>(T, M, Tq, Mq, tn, mn);
  gemm_epi_kernel<<<1024, 512, smem_bytes, stream>>>(Tq, Mq, tn, mn, groups, part);
  finalize1_kernel<<<Bn / 256, 256, 0, stream>>>(part, bsum);
  finalize2_kernel<<<1, 64, 0, stream>>>(bsum, (float*)d_out);
}